// Round 3
// baseline (29.428 us; speedup 1.0000x reference)
//
#include <hip/hip_runtime.h>

#define BATCH 4096
#define NCTRL 64
#define SDIM  2048
#define SBLK  256
#define VPT   4
#define CHUNK (SBLK * VPT)   // 1024 samples per block

typedef float f32x4 __attribute__((ext_vector_type(4)));  // native vector for nontemporal

__global__ __launch_bounds__(SBLK) void curve_eval_kernel(
    const float4* __restrict__ cp,     // [B, NCTRL] as float4 (x,y,z,w)
    const int*    __restrict__ span,   // [SDIM]
    const float4* __restrict__ basis,  // [SDIM] as float4
    f32x4*        __restrict__ out)    // [B*SDIM*3/4] float4
{
    __shared__ float4 cp_s[NCTRL];
    __shared__ float  out_s[CHUNK * 3];   // 12 KB

    const int b   = blockIdx.y;
    const int s0  = blockIdx.x * CHUNK;
    const int tid = threadIdx.x;

    // Stage this curve's control points into LDS (1 KB).
    if (tid < NCTRL) {
        cp_s[tid] = cp[(size_t)b * NCTRL + tid];
    }
    __syncthreads();

    // Each thread computes VPT samples, strided by SBLK for coalesced
    // span/basis reads.
    #pragma unroll
    for (int k = 0; k < VPT; ++k) {
        const int ls = tid + k * SBLK;       // local sample index in chunk
        const int s  = s0 + ls;
        const int sp = span[s];              // in [3, 63]
        const float4 bas = basis[s];

        const float4 r0 = cp_s[sp - 3];
        const float4 r1 = cp_s[sp - 2];
        const float4 r2 = cp_s[sp - 1];
        const float4 r3 = cp_s[sp - 0];

        const float x = bas.x * r0.x + bas.y * r1.x + bas.z * r2.x + bas.w * r3.x;
        const float y = bas.x * r0.y + bas.y * r1.y + bas.z * r2.y + bas.w * r3.y;
        const float z = bas.x * r0.z + bas.y * r1.z + bas.z * r2.z + bas.w * r3.z;
        const float w = bas.x * r0.w + bas.y * r1.w + bas.z * r2.w + bas.w * r3.w;

        const float invw = 1.0f / w;
        // stride-3 LDS writes: spread over banks, at most 2-way over 64 lanes
        out_s[ls * 3 + 0] = x * invw;
        out_s[ls * 3 + 1] = y * invw;
        out_s[ls * 3 + 2] = z * invw;
    }
    __syncthreads();

    // Coalesced flush: 1024*3 floats = 768 float4 per block, fully contiguous.
    // All 256 threads store 3 float4 each. Nontemporal: write-once stream.
    const f32x4* out_s4 = reinterpret_cast<const f32x4*>(out_s);
    const size_t base4 = ((size_t)b * SDIM + (size_t)s0) * 3u / 4u;
    #pragma unroll
    for (int k = 0; k < 3; ++k) {
        __builtin_nontemporal_store(out_s4[tid + k * SBLK],
                                    &out[base4 + tid + k * SBLK]);
    }
}

extern "C" void kernel_launch(void* const* d_in, const int* in_sizes, int n_in,
                              void* d_out, int out_size, void* d_ws, size_t ws_size,
                              hipStream_t stream) {
    const float4* cp    = (const float4*)d_in[0];  // [4096,64,4] f32
    const int*    span  = (const int*)d_in[1];     // [2048] i32
    const float4* basis = (const float4*)d_in[2];  // [2048,4] f32
    f32x4*        out   = (f32x4*)d_out;           // [4096,2048,3] f32

    dim3 grid(SDIM / CHUNK, BATCH);
    curve_eval_kernel<<<grid, SBLK, 0, stream>>>(cp, span, basis, out);
}

// Round 4
// 26.302 us; speedup vs baseline: 1.1188x; 1.1188x over previous
//
#include <hip/hip_runtime.h>

#define BATCH 4096
#define NCTRL 64
#define SDIM  2048
#define SBLK  256
#define VPT   4
#define CHUNK (SBLK * VPT)   // 1024 samples per block

__global__ __launch_bounds__(SBLK) void curve_eval_kernel(
    const float4* __restrict__ cp,     // [B, NCTRL] as float4 (x,y,z,w)
    const int*    __restrict__ span,   // [SDIM]
    const float4* __restrict__ basis,  // [SDIM] as float4
    float4*       __restrict__ out)    // [B*SDIM*3/4] float4
{
    __shared__ float4 cp_s[NCTRL];
    __shared__ float  out_s[CHUNK * 3];   // 12 KB

    const int b   = blockIdx.y;
    const int s0  = blockIdx.x * CHUNK;
    const int tid = threadIdx.x;

    // Issue ALL independent global loads up front: span/basis for the 4
    // samples this thread owns, plus the cp staging load. Their latencies
    // overlap each other instead of serializing across the barrier.
    int    sp_r [VPT];
    float4 bas_r[VPT];
    #pragma unroll
    for (int k = 0; k < VPT; ++k) {
        const int s = s0 + tid + k * SBLK;
        sp_r [k] = span[s];
        bas_r[k] = basis[s];
    }
    if (tid < NCTRL) {
        cp_s[tid] = cp[(size_t)b * NCTRL + tid];
    }
    __syncthreads();

    #pragma unroll
    for (int k = 0; k < VPT; ++k) {
        const int ls = tid + k * SBLK;       // local sample index in chunk
        const int sp = sp_r[k];              // in [3, 63]
        const float4 bas = bas_r[k];

        const float4 r0 = cp_s[sp - 3];
        const float4 r1 = cp_s[sp - 2];
        const float4 r2 = cp_s[sp - 1];
        const float4 r3 = cp_s[sp - 0];

        const float x = bas.x * r0.x + bas.y * r1.x + bas.z * r2.x + bas.w * r3.x;
        const float y = bas.x * r0.y + bas.y * r1.y + bas.z * r2.y + bas.w * r3.y;
        const float z = bas.x * r0.z + bas.y * r1.z + bas.z * r2.z + bas.w * r3.z;
        const float w = bas.x * r0.w + bas.y * r1.w + bas.z * r2.w + bas.w * r3.w;

        const float invw = 1.0f / w;
        // stride-3 LDS writes: 2-way aliasing max over 64 lanes, free
        out_s[ls * 3 + 0] = x * invw;
        out_s[ls * 3 + 1] = y * invw;
        out_s[ls * 3 + 2] = z * invw;
    }
    __syncthreads();

    // Coalesced flush: 1024*3 floats = 768 float4 per block, fully
    // contiguous; all 256 threads store 3 float4 each. Plain stores
    // (NT isolated out — R3 regression suspect).
    const float4* out_s4 = reinterpret_cast<const float4*>(out_s);
    const size_t base4 = ((size_t)b * SDIM + (size_t)s0) * 3u / 4u;
    #pragma unroll
    for (int k = 0; k < 3; ++k) {
        out[base4 + tid + k * SBLK] = out_s4[tid + k * SBLK];
    }
}

extern "C" void kernel_launch(void* const* d_in, const int* in_sizes, int n_in,
                              void* d_out, int out_size, void* d_ws, size_t ws_size,
                              hipStream_t stream) {
    const float4* cp    = (const float4*)d_in[0];  // [4096,64,4] f32
    const int*    span  = (const int*)d_in[1];     // [2048] i32
    const float4* basis = (const float4*)d_in[2];  // [2048,4] f32
    float4*       out   = (float4*)d_out;          // [4096,2048,3] f32

    dim3 grid(SDIM / CHUNK, BATCH);
    curve_eval_kernel<<<grid, SBLK, 0, stream>>>(cp, span, basis, out);
}

// Round 5
// 26.142 us; speedup vs baseline: 1.1257x; 1.0061x over previous
//
#include <hip/hip_runtime.h>

#define BATCH 4096
#define NCTRL 64
#define SDIM  2048
#define WSZ   64                 // 1 wave per block
#define VPT   4
#define CHUNK (WSZ * VPT)        // 256 samples per block

__global__ __launch_bounds__(WSZ, 8) void curve_eval_kernel(
    const float4* __restrict__ cp,     // [B, NCTRL] as float4 (x,y,z,w)
    const int*    __restrict__ span,   // [SDIM]
    const float4* __restrict__ basis,  // [SDIM] as float4
    float4*       __restrict__ out)    // [B*SDIM*3/4] float4
{
    __shared__ float4 cp_s[NCTRL];       // 1 KB
    __shared__ float  out_s[CHUNK * 3];  // 3 KB

    const int b   = blockIdx.y;
    const int s0  = blockIdx.x * CHUNK;
    const int tid = threadIdx.x;         // 0..63

    // Stage this curve's control points: one b128 load + one ds_write per lane.
    cp_s[tid] = cp[(size_t)b * NCTRL + tid];
    __syncthreads();   // single-wave workgroup: compiles to waitcnt (+ trivial barrier)

    #pragma unroll
    for (int k = 0; k < VPT; ++k) {
        const int ls = tid + k * WSZ;        // local sample index in chunk
        const int s  = s0 + ls;
        const int sp = span[s];              // in [3, 63]
        const float4 bas = basis[s];

        const float4 r0 = cp_s[sp - 3];
        const float4 r1 = cp_s[sp - 2];
        const float4 r2 = cp_s[sp - 1];
        const float4 r3 = cp_s[sp - 0];

        const float x = bas.x * r0.x + bas.y * r1.x + bas.z * r2.x + bas.w * r3.x;
        const float y = bas.x * r0.y + bas.y * r1.y + bas.z * r2.y + bas.w * r3.y;
        const float z = bas.x * r0.z + bas.y * r1.z + bas.z * r2.z + bas.w * r3.z;
        const float w = bas.x * r0.w + bas.y * r1.w + bas.z * r2.w + bas.w * r3.w;

        // Fast reciprocal: ~2^-22 rel error, absmax headroom is 5x -> safe.
        const float invw = __builtin_amdgcn_rcpf(w);
        out_s[ls * 3 + 0] = x * invw;        // stride-3: <=2-way bank alias, free
        out_s[ls * 3 + 1] = y * invw;
        out_s[ls * 3 + 2] = z * invw;
    }
    __syncthreads();

    // Coalesced flush: 256*3 floats = 192 float4, contiguous; 3 per lane.
    const float4* out_s4 = reinterpret_cast<const float4*>(out_s);
    const size_t base4 = ((size_t)b * SDIM + (size_t)s0) * 3u / 4u;
    #pragma unroll
    for (int k = 0; k < 3; ++k) {
        out[base4 + tid + k * WSZ] = out_s4[tid + k * WSZ];
    }
}

extern "C" void kernel_launch(void* const* d_in, const int* in_sizes, int n_in,
                              void* d_out, int out_size, void* d_ws, size_t ws_size,
                              hipStream_t stream) {
    const float4* cp    = (const float4*)d_in[0];  // [4096,64,4] f32
    const int*    span  = (const int*)d_in[1];     // [2048] i32
    const float4* basis = (const float4*)d_in[2];  // [2048,4] f32
    float4*       out   = (float4*)d_out;          // [4096,2048,3] f32

    dim3 grid(SDIM / CHUNK, BATCH);                // 8 x 4096 = 32768 one-wave blocks
    curve_eval_kernel<<<grid, WSZ, 0, stream>>>(cp, span, basis, out);
}